// Round 18
// baseline (132.418 us; speedup 1.0000x reference)
//
#include <hip/hip_runtime.h>

// MHA: B=2, S=2048, D=1024, H=16, DK=DV=64
// Round 18: fused-pair flash. s0 block processes q-block p AND mirror 15-p in
// ONE tile loop (P active t<2p+2, mirror active t<T0), T0 balanced per-p so
// s0/s1 blocks run equal tiles ({16,15,14,13,12,12,14,16}): -18% tile-passes,
// -18% staging/barriers, critical path 17->16. Sequential per-tile processing
// keeps one sacc/pk set live (~230 VGPR, no launch_bounds cap -> 2 waves/SIMD,
// no spill). Combine is split-agnostic. Rest = r17 (best, 109.5us).

#define DI __device__ __forceinline__

typedef __bf16 bf16x8 __attribute__((ext_vector_type(8)));
typedef float f32x4 __attribute__((ext_vector_type(4)));
typedef unsigned short u16x8 __attribute__((ext_vector_type(8)));
typedef unsigned short u16x4 __attribute__((ext_vector_type(4)));

union U8 { u16x8 u; bf16x8 b; };
union PB { unsigned int w[4]; u16x8 u; bf16x8 b; };

typedef const __attribute__((address_space(1))) unsigned int* gas_p;
typedef __attribute__((address_space(3))) unsigned int* las_p;

DI void gload16(const unsigned short* g, unsigned short* l) {
  __builtin_amdgcn_global_load_lds((gas_p)(const void*)g, (las_p)(void*)l, 16, 0, 0);
}

#define WAIT_VM4  asm volatile("s_waitcnt vmcnt(4)" ::: "memory")
#define WAIT_VM0  asm volatile("s_waitcnt vmcnt(0)" ::: "memory")
#define BARRIER   __builtin_amdgcn_s_barrier()

DI unsigned short f2bf(float f) {            // round-to-nearest-even
  unsigned int u = __float_as_uint(f);
  u += 0x7FFFu + ((u >> 16) & 1u);
  return (unsigned short)(u >> 16);
}
DI float bf2f(unsigned short v) { return __uint_as_float((unsigned int)v << 16); }

// ---------------- kernel 0: W transpose (z<4) + x conversion (z>=4) ----------
__global__ void k_prep(
    const float* __restrict__ W0, const float* __restrict__ W1,
    const float* __restrict__ W2, const float* __restrict__ W3,
    unsigned short* __restrict__ T0, unsigned short* __restrict__ T1,
    unsigned short* __restrict__ T2, unsigned short* __restrict__ T3,
    const float* __restrict__ x, unsigned short* __restrict__ xb) {
  const int z = blockIdx.z;
  const int tx = threadIdx.x, ty = threadIdx.y;   // (32, 8)
  if (z >= 4) {
    int chunk = (z - 4) * 1024 + blockIdx.y * 32 + blockIdx.x;
    size_t i = ((size_t)chunk * 256 + ty * 32 + tx) * 4;
    float4 v = *(const float4*)(x + i);
    u16x4 o;
    o[0] = f2bf(v.x); o[1] = f2bf(v.y); o[2] = f2bf(v.z); o[3] = f2bf(v.w);
    *(u16x4*)(xb + i) = o;
    return;
  }
  const float* W = (z == 0) ? W0 : (z == 1) ? W1 : (z == 2) ? W2 : W3;
  unsigned short* T = (z == 0) ? T0 : (z == 1) ? T1 : (z == 2) ? T2 : T3;
  __shared__ unsigned short buf[32][33];
  const int k0 = blockIdx.x * 32, n0 = blockIdx.y * 32;
#pragma unroll
  for (int j = 0; j < 4; ++j) {
    int r = ty + j * 8;
    buf[r][tx] = f2bf(W[(size_t)(k0 + r) * 1024 + n0 + tx]);
  }
  __syncthreads();
#pragma unroll
  for (int j = 0; j < 4; ++j) {
    int c = ty + j * 8;
    T[(size_t)(n0 + c) * 1024 + k0 + tx] = buf[tx][c];
  }
}

// ---------------- shared GEMM main loop (BK=32, gload_lds + dbuf) ------------
DI void stage_gemm(const unsigned short* __restrict__ src, unsigned short* dst,
                   int row0, int k0, int tid, int wid) {
#pragma unroll
  for (int i = 0; i < 2; ++i) {
    int T = i * 256 + tid;
    int row = T >> 2, ch = T & 3;
    int sch = ch ^ (row & 3);
    gload16(&src[(size_t)(row0 + row) * 1024 + k0 + sch * 8],
            &dst[(i * 256 + wid * 64) * 8]);
  }
}

DI void gemm_main(const unsigned short* __restrict__ A,
                  const unsigned short* __restrict__ Bm,
                  unsigned short* As, unsigned short* Bs,
                  int m0, int n0, f32x4 acc[4][4]) {
  const int tid = threadIdx.x;
  const int lane = tid & 63, wid = tid >> 6;
  const int wr = wid >> 1, wc = wid & 1;
  const int g = lane >> 4, lq = lane & 15;

  stage_gemm(A, As, m0, 0, tid, wid);
  stage_gemm(Bm, Bs, n0, 0, tid, wid);
  __syncthreads();
  int buf = 0;
  for (int k0 = 0; k0 < 1024; k0 += 32) {
    if (k0 + 32 < 1024) {
      stage_gemm(A, As + (buf ^ 1) * 4096, m0, k0 + 32, tid, wid);
      stage_gemm(Bm, Bs + (buf ^ 1) * 4096, n0, k0 + 32, tid, wid);
    }
    const unsigned short* Ab = As + buf * 4096;
    const unsigned short* Bb = Bs + buf * 4096;
    U8 af[4], bfr[4];
#pragma unroll
    for (int f = 0; f < 4; ++f) {
      af[f].u  = *(const u16x8*)&Ab[(wr * 64 + f * 16 + lq) * 32 + ((g ^ (lq & 3)) * 8)];
      bfr[f].u = *(const u16x8*)&Bb[(wc * 64 + f * 16 + lq) * 32 + ((g ^ (lq & 3)) * 8)];
    }
#pragma unroll
    for (int i = 0; i < 4; ++i)
#pragma unroll
      for (int j = 0; j < 4; ++j)
        acc[i][j] = __builtin_amdgcn_mfma_f32_16x16x32_bf16(af[i].b, bfr[j].b,
                                                            acc[i][j], 0, 0, 0);
    __syncthreads();
    buf ^= 1;
  }
}

// ---------------- kernel 1: QKV projection (LDS-restaged epilogue) ----------
__global__ __launch_bounds__(256) void k_gemm_qkv(
    const unsigned short* __restrict__ xb,
    const unsigned short* __restrict__ Wqt, const unsigned short* __restrict__ Wkt,
    const unsigned short* __restrict__ Wvt,
    const float* __restrict__ bq, const float* __restrict__ bk,
    const float* __restrict__ bv,
    unsigned short* __restrict__ Qo, unsigned short* __restrict__ Ko,
    unsigned short* __restrict__ Vto) {
  __shared__ unsigned short Sh[128 * 136];   // dbuf (16384) + epilogue tile
  unsigned short* As = Sh;
  unsigned short* Bs = Sh + 8192;
  const int z = blockIdx.z;
  const unsigned short* Bm = (z == 0) ? Wqt : (z == 1) ? Wkt : Wvt;
  const float* bias = (z == 0) ? bq : (z == 1) ? bk : bv;

  f32x4 acc[4][4];
#pragma unroll
  for (int i = 0; i < 4; ++i)
#pragma unroll
    for (int j = 0; j < 4; ++j) acc[i][j] = f32x4{0.f, 0.f, 0.f, 0.f};

  const int m0 = blockIdx.x * 128, n0 = blockIdx.y * 128;
  gemm_main(xb, Bm, As, Bs, m0, n0, acc);

  const int tid = threadIdx.x;
  const int lane = tid & 63, wid = tid >> 6;
  const int wr = wid >> 1, wc = wid & 1;
  const int g = lane >> 4, lq = lane & 15;
  const int bb = m0 >> 11;   // batch (128-row tile within one batch)

#pragma unroll
  for (int j = 0; j < 4; ++j) {
    int col = wc * 64 + j * 16 + lq;
    float bv_ = bias[n0 + col];
#pragma unroll
    for (int i = 0; i < 4; ++i)
#pragma unroll
      for (int r = 0; r < 4; ++r) {
        int row = wr * 64 + i * 16 + g * 4 + r;
        Sh[row * 136 + col] = f2bf(acc[i][j][r] + bv_);
      }
  }
  __syncthreads();

  if (z < 2) {
    unsigned short* dstQK = (z == 0) ? Qo : Ko;
    const int ch = tid & 15, sb = tid >> 4;
#pragma unroll
    for (int it = 0; it < 8; ++it) {
      int s = sb + it * 16;
      u16x8 v = *(const u16x8*)&Sh[s * 136 + ch * 8];
      int gcol = n0 + ch * 8;
      int hh = gcol >> 6, dd = gcol & 63;
      int sr = (m0 + s) & 2047;
      *(u16x8*)&dstQK[(((size_t)(bb * 16 + hh)) * 2048 + sr) * 64 + dd] = v;
    }
  } else {
    const int d = tid & 127, hf = tid >> 7;
    int gcol = n0 + d;
    int hh = gcol >> 6, dd = gcol & 63;
    size_t vrow = ((size_t)(bb * 16 + hh)) * 64 + dd;
#pragma unroll
    for (int it = 0; it < 8; ++it) {
      int s0 = (hf + it * 2) * 8;
      u16x8 vv;
#pragma unroll
      for (int e = 0; e < 8; ++e) vv[e] = Sh[(s0 + e) * 136 + d];
      *(u16x8*)&Vto[vrow * 2048 + (m0 & 2047) + s0] = vv;
    }
  }
}

// ---------------- kernel 3: output projection (fp32 out + bias) ----------------
__global__ __launch_bounds__(256) void k_gemm_out(
    const unsigned short* __restrict__ Ob, const unsigned short* __restrict__ Wot,
    const float* __restrict__ bo, float* __restrict__ out) {
  __shared__ unsigned short As[2 * 4096];
  __shared__ unsigned short Bs[2 * 4096];
  f32x4 acc[4][4];
#pragma unroll
  for (int i = 0; i < 4; ++i)
#pragma unroll
    for (int j = 0; j < 4; ++j) acc[i][j] = f32x4{0.f, 0.f, 0.f, 0.f};

  const int m0 = blockIdx.x * 128, n0 = blockIdx.y * 128;
  gemm_main(Ob, Wot, As, Bs, m0, n0, acc);

  const int lane = threadIdx.x & 63, wid = threadIdx.x >> 6;
  const int wr = wid >> 1, wc = wid & 1;
  const int g = lane >> 4, lq = lane & 15;
#pragma unroll
  for (int j = 0; j < 4; ++j) {
    int col = n0 + wc * 64 + j * 16 + lq;
    float bv_ = bo[col];
#pragma unroll
    for (int i = 0; i < 4; ++i)
#pragma unroll
      for (int r = 0; r < 4; ++r) {
        int row = m0 + wr * 64 + i * 16 + g * 4 + r;
        out[(size_t)row * 1024 + col] = acc[i][j][r] + bv_;
      }
  }
}

// ---------------- flash attention common pieces -------------------------------
template<bool MASKED>
DI void ptile(f32x4 sacc[4], f32x4& lacc, unsigned int pk[4][2],
              int qrow, int kk0, int g) {
  const float SC = 0.18033688011112042f;   // 0.125 * log2(e)
#pragma unroll
  for (int c = 0; c < 4; ++c) {
#pragma unroll
    for (int r = 0; r < 4; ++r) {
      float sv = fabsf(sacc[c][r]) * SC;
      if (MASKED) {
        int k = kk0 + g * 8 + r + 4 * (c & 1) + 32 * (c >> 1);
        sv = (k <= qrow) ? sv : -1e30f;
      }
      float p = exp2f(sv);
      sacc[c][r] = p;
      lacc[r] += p;
    }
    asm("v_cvt_pk_bf16_f32 %0, %1, %2"
        : "=v"(pk[c][0]) : "v"(sacc[c][0]), "v"(sacc[c][1]));
    asm("v_cvt_pk_bf16_f32 %0, %1, %2"
        : "=v"(pk[c][1]) : "v"(sacc[c][2]), "v"(sacc[c][3]));
  }
}

// One dual-group q-block step for tile in Kb/Vb: QK^T -> softmax -> PV.
DI void qblock_step(bool masked, int qrowA, int qrowB, int kk0,
                    const unsigned short* Kb, const unsigned short* Vb,
                    const U8& aq0A, const U8& aq1A, const U8& aq0B, const U8& aq1B,
                    f32x4& laccA, f32x4& laccB, f32x4 oaccA[4], f32x4 oaccB[4],
                    int rbase, int g, int lq) {
  f32x4 saccA[4], saccB[4];
  __builtin_amdgcn_s_setprio(1);
#pragma unroll
  for (int c = 0; c < 4; ++c) {
    int row = rbase + 4 * (c & 1) + 32 * (c >> 1);
    int r7 = row & 7;
    U8 kf0, kf1;
    kf0.u = *(const u16x8*)&Kb[row * 64 + ((g ^ r7) * 8)];
    kf1.u = *(const u16x8*)&Kb[row * 64 + (((4 + g) ^ r7) * 8)];
    saccA[c] = __builtin_amdgcn_mfma_f32_16x16x32_bf16(kf0.b, aq0A.b,
                                                       f32x4{0.f, 0.f, 0.f, 0.f}, 0, 0, 0);
    saccA[c] = __builtin_amdgcn_mfma_f32_16x16x32_bf16(kf1.b, aq1A.b, saccA[c], 0, 0, 0);
    saccB[c] = __builtin_amdgcn_mfma_f32_16x16x32_bf16(kf0.b, aq0B.b,
                                                       f32x4{0.f, 0.f, 0.f, 0.f}, 0, 0, 0);
    saccB[c] = __builtin_amdgcn_mfma_f32_16x16x32_bf16(kf1.b, aq1B.b, saccB[c], 0, 0, 0);
  }
  __builtin_amdgcn_s_setprio(0);
  unsigned int pkA[4][2], pkB[4][2];
  if (masked) {
    ptile<true>(saccA, laccA, pkA, qrowA, kk0, g);
    ptile<true>(saccB, laccB, pkB, qrowB, kk0, g);
  } else {
    ptile<false>(saccA, laccA, pkA, qrowA, kk0, g);
    ptile<false>(saccB, laccB, pkB, qrowB, kk0, g);
  }
  __builtin_amdgcn_s_setprio(1);
#pragma unroll
  for (int hh = 0; hh < 2; ++hh) {
    PB pbA, pbB;
    pbA.w[0] = pkA[hh * 2 + 0][0]; pbA.w[1] = pkA[hh * 2 + 0][1];
    pbA.w[2] = pkA[hh * 2 + 1][0]; pbA.w[3] = pkA[hh * 2 + 1][1];
    pbB.w[0] = pkB[hh * 2 + 0][0]; pbB.w[1] = pkB[hh * 2 + 0][1];
    pbB.w[2] = pkB[hh * 2 + 1][0]; pbB.w[3] = pkB[hh * 2 + 1][1];
#pragma unroll
    for (int c = 0; c < 4; ++c) {
      U8 vf;
      vf.u = *(const u16x8*)&Vb[(c * 16 + lq) * 64 + (((hh * 4 + g) ^ (lq & 7)) * 8)];
      oaccA[c] = __builtin_amdgcn_mfma_f32_16x16x32_bf16(vf.b, pbA.b, oaccA[c], 0, 0, 0);
      oaccB[c] = __builtin_amdgcn_mfma_f32_16x16x32_bf16(vf.b, pbB.b, oaccB[c], 0, 0, 0);
    }
  }
  __builtin_amdgcn_s_setprio(0);
}

DI void epilogue_complete(f32x4 oaccA[4], f32x4 oaccB[4], f32x4& laccA, f32x4& laccB,
                          unsigned short* O, int b, int h, int qrowA, int qrowB, int g) {
  float lsA = (laccA[0] + laccA[1]) + (laccA[2] + laccA[3]);
  lsA += __shfl_xor(lsA, 16, 64);
  lsA += __shfl_xor(lsA, 32, 64);
  float lsB = (laccB[0] + laccB[1]) + (laccB[2] + laccB[3]);
  lsB += __shfl_xor(lsB, 16, 64);
  lsB += __shfl_xor(lsB, 32, 64);
  float invA = 1.0f / lsA, invB = 1.0f / lsB;
#pragma unroll
  for (int c = 0; c < 4; ++c) {
    u16x4 ovA, ovB;
#pragma unroll
    for (int r2 = 0; r2 < 4; ++r2) {
      ovA[r2] = f2bf(oaccA[c][r2] * invA);
      ovB[r2] = f2bf(oaccB[c][r2] * invB);
    }
    *(u16x4*)&O[((size_t)(b * 2048 + qrowA)) * 1024 + h * 64 + c * 16 + g * 4] = ovA;
    *(u16x4*)&O[((size_t)(b * 2048 + qrowB)) * 1024 + h * 64 + c * 16 + g * 4] = ovB;
  }
}

DI void epilogue_partial(f32x4 oaccA[4], f32x4 oaccB[4], f32x4& laccA, f32x4& laccB,
                         unsigned short* Pp, float* Lp, int slot,
                         int lrowA, int lrowB, int g) {
  float lsA = (laccA[0] + laccA[1]) + (laccA[2] + laccA[3]);
  lsA += __shfl_xor(lsA, 16, 64);
  lsA += __shfl_xor(lsA, 32, 64);
  float lsB = (laccB[0] + laccB[1]) + (laccB[2] + laccB[3]);
  lsB += __shfl_xor(lsB, 16, 64);
  lsB += __shfl_xor(lsB, 32, 64);
  if (g == 0) {
    Lp[slot * 128 + lrowA] = lsA;
    Lp[slot * 128 + lrowB] = lsB;
  }
  size_t pbase = (size_t)slot * 8192;
#pragma unroll
  for (int c = 0; c < 4; ++c) {
    u16x4 ovA, ovB;
#pragma unroll
    for (int r2 = 0; r2 < 4; ++r2) {
      ovA[r2] = f2bf(oaccA[c][r2]);
      ovB[r2] = f2bf(oaccB[c][r2]);
    }
    *(u16x4*)&Pp[pbase + lrowA * 64 + c * 16 + g * 4] = ovA;
    *(u16x4*)&Pp[pbase + lrowB * 64 + c * 16 + g * 4] = ovB;
  }
}

// ---------------- kernel 2: flash attention v18 -------------------------------
// s0: fused pair -- ONE tile loop over [0, TE), P-block (p) active t<2p+2
// (complete, direct write), mirror (15-p) active t<T0 (partial slot 0).
// s1: mirror tiles [T0, 32-2p) (partial slot 1, includes its diagonal).
__global__ __launch_bounds__(256) void k_flash(
    const unsigned short* __restrict__ Q, const unsigned short* __restrict__ Km,
    const unsigned short* __restrict__ Vt, unsigned short* __restrict__ O,
    unsigned short* __restrict__ Pp, float* __restrict__ Lp) {
  __shared__ unsigned short Ks[3 * 4096];
  __shared__ unsigned short Vs[3 * 4096];
  const int tid = threadIdx.x;
  const int lane = tid & 63, wid = tid >> 6;
  const int g = lane >> 4, lq = lane & 15;
  const int bid = blockIdx.x;               // 512 blocks
  const int xcd = bid & 7, idx = bid >> 3;  // 64 per XCD
  const int bh = xcd * 4 + (idx >> 4);      // 4 bh per XCD
  const int rr = idx & 15;
  const int p = rr >> 1, sp = rr & 1;       // pair p in 0..7
  const int mp = 15 - p;
  const int b = bh >> 4, h = bh & 15;
  const size_t qkbase = (size_t)bh * 2048 * 64;
  const size_t vbase = (size_t)bh * 64 * 2048;
  const int T0 = (p <= 4) ? (16 - p) : ((p == 5) ? 10 : ((p == 6) ? 6 : 2));
  const int lrowA = wid * 32 + lq, lrowB = lrowA + 16;
  const int rbase = (lq >> 2) * 8 + (lq & 3);

  auto stage = [&](int bf, int t) {           // 4 gload16/thread
    const int kk0 = t * 64;
#pragma unroll
    for (int i = 0; i < 2; ++i) {
      int T = i * 256 + tid;
      int row = T >> 3, ch = T & 7;
      int sch = ch ^ (row & 7);
      gload16(&Km[qkbase + (size_t)(kk0 + row) * 64 + sch * 8],
              Ks + bf * 4096 + (i * 2048 + wid * 512));
      gload16(&Vt[vbase + (size_t)row * 2048 + kk0 + sch * 8],
              Vs + bf * 4096 + (i * 2048 + wid * 512));
    }
  };

  if (sp == 0) {
    // ---- fused pair: P = q-block p (complete) + M = mirror head [0, T0)
    const int ntP = 2 * p + 2;
    const int TE = (ntP > T0) ? ntP : T0;
    const int qrowPA = p * 128 + lrowA, qrowPB = p * 128 + lrowB;
    const int qrowMA = mp * 128 + lrowA, qrowMB = mp * 128 + lrowB;
    const int diagP = 2 * p;

    U8 aqPA0, aqPA1, aqPB0, aqPB1, aqMA0, aqMA1, aqMB0, aqMB1;
    {
      const unsigned short* qp;
      qp = &Q[qkbase + (size_t)qrowPA * 64 + g * 8];
      aqPA0.u = *(const u16x8*)qp; aqPA1.u = *(const u16x8*)(qp + 32);
      qp = &Q[qkbase + (size_t)qrowPB * 64 + g * 8];
      aqPB0.u = *(const u16x8*)qp; aqPB1.u = *(const u16x8*)(qp + 32);
      qp = &Q[qkbase + (size_t)qrowMA * 64 + g * 8];
      aqMA0.u = *(const u16x8*)qp; aqMA1.u = *(const u16x8*)(qp + 32);
      qp = &Q[qkbase + (size_t)qrowMB * 64 + g * 8];
      aqMB0.u = *(const u16x8*)qp; aqMB1.u = *(const u16x8*)(qp + 32);
    }
    f32x4 laccPA = f32x4{0.f,0.f,0.f,0.f}, laccPB = f32x4{0.f,0.f,0.f,0.f};
    f32x4 laccMA = f32x4{0.f,0.f,0.f,0.f}, laccMB = f32x4{0.f,0.f,0.f,0.f};
    f32x4 oaccPA[4], oaccPB[4], oaccMA[4], oaccMB[4];
#pragma unroll
    for (int c = 0; c < 4; ++c) {
      oaccPA[c] = f32x4{0.f,0.f,0.f,0.f}; oaccPB[c] = f32x4{0.f,0.f,0.f,0.f};
      oaccMA[c] = f32x4{0.f,0.f,0.f,0.f}; oaccMB[c] = f32x4{0.f,0.f,0.f,0.f};
    }

    stage(0, 0);
    if (1 < TE) stage(1, 1);
    int bi = 0;
    for (int t = 0; t < TE; ++t) {
      if (t + 1 < TE) WAIT_VM4; else WAIT_VM0;
      BARRIER;
      if (t + 2 < TE) {
        int nb = bi + 2; if (nb >= 3) nb -= 3;
        stage(nb, t + 2);
      }
      const unsigned short* Kb = Ks + bi * 4096;
      const unsigned short* Vb = Vs + bi * 4096;
      const int kk0 = t * 64;
      if (t < ntP)
        qblock_step(t >= diagP, qrowPA, qrowPB, kk0, Kb, Vb,
                    aqPA0, aqPA1, aqPB0, aqPB1, laccPA, laccPB, oaccPA, oaccPB,
                    rbase, g, lq);
      if (t < T0)
        qblock_step(false, qrowMA, qrowMB, kk0, Kb, Vb,
                    aqMA0, aqMA1, aqMB0, aqMB1, laccMA, laccMB, oaccMA, oaccMB,
                    rbase, g, lq);
      ++bi; if (bi >= 3) bi = 0;
    }
    epilogue_complete(oaccPA, oaccPB, laccPA, laccPB, O, b, h, qrowPA, qrowPB, g);
    epilogue_partial(oaccMA, oaccMB, laccMA, laccMB, Pp, Lp,
                     (bh * 8 + p) * 2 + 0, lrowA, lrowB, g);
  } else {
    // ---- mirror tail: tiles [T0, 32-2p), includes mirror diagonal
    const int t0 = T0, t1 = 32 - 2 * p;
    const int qrowMA = mp * 128 + lrowA, qrowMB = mp * 128 + lrowB;
    const int diagM = 2 * mp;

    U8 aqMA0, aqMA1, aqMB0, aqMB1;
    {
      const unsigned short* qp;
      qp = &Q[qkbase + (size_t)qrowMA * 64 + g * 8];
      aqMA0.u = *(const u16x8*)qp; aqMA1.u = *(const u16x8*)(qp + 32);
      qp = &Q[qkbase + (size_t)qrowMB * 64 + g * 8];
      aqMB0.u = *(const u16x8*)qp; aqMB1.u = *(const u16x8*)(qp + 32);
    }
    f32x4 laccMA = f32x4{0.f,0.f,0.f,0.f}, laccMB = f32x4{0.f,0.f,0.f,0.f};
    f32x4 oaccMA[4], oaccMB[4];
#pragma unroll
    for (int c = 0; c < 4; ++c) {
      oaccMA[c] = f32x4{0.f,0.f,0.f,0.f};
      oaccMB[c] = f32x4{0.f,0.f,0.f,0.f};
    }

    stage(0, t0);
    if (t0 + 1 < t1) stage(1, t0 + 1);
    int bi = 0;
    for (int t = t0; t < t1; ++t) {
      if (t + 1 < t1) WAIT_VM4; else WAIT_VM0;
      BARRIER;
      if (t + 2 < t1) {
        int nb = bi + 2; if (nb >= 3) nb -= 3;
        stage(nb, t + 2);
      }
      const unsigned short* Kb = Ks + bi * 4096;
      const unsigned short* Vb = Vs + bi * 4096;
      qblock_step(t >= diagM, qrowMA, qrowMB, t * 64, Kb, Vb,
                  aqMA0, aqMA1, aqMB0, aqMB1, laccMA, laccMB, oaccMA, oaccMB,
                  rbase, g, lq);
      ++bi; if (bi >= 3) bi = 0;
    }
    epilogue_partial(oaccMA, oaccMB, laccMA, laccMB, Pp, Lp,
                     (bh * 8 + p) * 2 + 1, lrowA, lrowB, g);
  }
}

// ---------------- kernel 2b: combine mirror partials (128-row slots) ---------
__global__ __launch_bounds__(256) void k_combine(
    const unsigned short* __restrict__ Pp, const float* __restrict__ Lp,
    unsigned short* __restrict__ O) {
  int gid = blockIdx.x * 256 + threadIdx.x;   // 524288 threads
  int dv4 = gid & 15;
  int q   = (gid >> 4) & 127;
  int pi  = (gid >> 11) & 7;
  int bh  = gid >> 14;
  int slot0 = (bh * 8 + pi) * 2;
  size_t base = (size_t)slot0 * 8192 + q * 64 + dv4 * 4;
  u16x4 a = *(const u16x4*)&Pp[base];
  u16x4 c = *(const u16x4*)&Pp[base + 8192];
  float l = Lp[slot0 * 128 + q] + Lp[(slot0 + 1) * 128 + q];
  float inv = 1.0f / l;
  u16x4 o;
#pragma unroll
  for (int r = 0; r < 4; ++r) o[r] = f2bf((bf2f(a[r]) + bf2f(c[r])) * inv);
  int b = bh >> 4, h = bh & 15;
  int srow = (15 - pi) * 128 + q;
  *(u16x4*)&O[((size_t)(b * 2048 + srow)) * 1024 + h * 64 + dv4 * 4] = o;
}

// ---------------- launch ----------------
extern "C" void kernel_launch(void* const* d_in, const int* in_sizes, int n_in,
                              void* d_out, int out_size, void* d_ws, size_t ws_size,
                              hipStream_t stream) {
  const float* x  = (const float*)d_in[0];
  const float* Wq = (const float*)d_in[1];
  const float* bq = (const float*)d_in[2];
  const float* Wk = (const float*)d_in[3];
  const float* bk = (const float*)d_in[4];
  const float* Wv = (const float*)d_in[5];
  const float* bv = (const float*)d_in[6];
  const float* Wo = (const float*)d_in[7];
  const float* bo = (const float*)d_in[8];
  float* out = (float*)d_out;

  char* ws = (char*)d_ws;
  const size_t MB = 1024 * 1024;
  unsigned short* xb   = (unsigned short*)(ws + 0 * MB);   // 8 MB (dead after qkv)
  unsigned short* Wqt  = (unsigned short*)(ws + 8 * MB);   // 2 MB (dead after qkv)
  unsigned short* Wkt  = (unsigned short*)(ws + 10 * MB);  // 2 MB
  unsigned short* Wvt  = (unsigned short*)(ws + 12 * MB);  // 2 MB
  unsigned short* Wot  = (unsigned short*)(ws + 14 * MB);  // 2 MB (used by out-proj)
  unsigned short* Qws  = (unsigned short*)(ws + 16 * MB);  // 8 MB
  unsigned short* Kws  = (unsigned short*)(ws + 24 * MB);  // 8 MB
  unsigned short* Vtws = (unsigned short*)(ws + 32 * MB);  // 8 MB
  unsigned short* Ows  = (unsigned short*)(ws + 40 * MB);  // 8 MB
  unsigned short* Pp   = (unsigned short*)(ws + 0 * MB);   // 8 MB, overlays xb
  float*          Lp   = (float*)(ws + 8 * MB);            // 256 KB, overlays Wqt

  k_prep<<<dim3(32, 32, 8), dim3(32, 8), 0, stream>>>(Wq, Wk, Wv, Wo,
                                                      Wqt, Wkt, Wvt, Wot, x, xb);
  k_gemm_qkv<<<dim3(32, 8, 3), 256, 0, stream>>>(xb, Wqt, Wkt, Wvt, bq, bk, bv,
                                                 Qws, Kws, Vtws);
  k_flash<<<512, 256, 0, stream>>>(Qws, Kws, Vtws, Ows, Pp, Lp);
  k_combine<<<2048, 256, 0, stream>>>(Pp, Lp, Ows);
  k_gemm_out<<<dim3(32, 8), 256, 0, stream>>>(Ows, Wot, bo, out);
}

// Round 19
// 109.244 us; speedup vs baseline: 1.2121x; 1.2121x over previous
//
#include <hip/hip_runtime.h>

// MHA: B=2, S=2048, D=1024, H=16, DK=DV=64
// Round 19: REVERT r18 (fused-pair flash: 4 live acc states -> 164 VGPR ->
// occupancy halved -> 71us). Restore r17 verbatim (best: 109.5us): 3-launch
// QKV (BK=32, 3 blocks/CU), r15 triple-buffer flash (512x256, dual-group
// 32q/wave, split-pair uniform, sigma zero-shuffle refrag, fixed-m exp2
// softmax), k_combine, out-proj, merged prep kernel.

#define DI __device__ __forceinline__

typedef __bf16 bf16x8 __attribute__((ext_vector_type(8)));
typedef float f32x4 __attribute__((ext_vector_type(4)));
typedef unsigned short u16x8 __attribute__((ext_vector_type(8)));
typedef unsigned short u16x4 __attribute__((ext_vector_type(4)));

union U8 { u16x8 u; bf16x8 b; };
union PB { unsigned int w[4]; u16x8 u; bf16x8 b; };

typedef const __attribute__((address_space(1))) unsigned int* gas_p;
typedef __attribute__((address_space(3))) unsigned int* las_p;

DI void gload16(const unsigned short* g, unsigned short* l) {
  __builtin_amdgcn_global_load_lds((gas_p)(const void*)g, (las_p)(void*)l, 16, 0, 0);
}

#define WAIT_VM4  asm volatile("s_waitcnt vmcnt(4)" ::: "memory")
#define WAIT_VM0  asm volatile("s_waitcnt vmcnt(0)" ::: "memory")
#define BARRIER   __builtin_amdgcn_s_barrier()

DI unsigned short f2bf(float f) {            // round-to-nearest-even
  unsigned int u = __float_as_uint(f);
  u += 0x7FFFu + ((u >> 16) & 1u);
  return (unsigned short)(u >> 16);
}
DI float bf2f(unsigned short v) { return __uint_as_float((unsigned int)v << 16); }

// ---------------- kernel 0: W transpose (z<4) + x conversion (z>=4) ----------
__global__ void k_prep(
    const float* __restrict__ W0, const float* __restrict__ W1,
    const float* __restrict__ W2, const float* __restrict__ W3,
    unsigned short* __restrict__ T0, unsigned short* __restrict__ T1,
    unsigned short* __restrict__ T2, unsigned short* __restrict__ T3,
    const float* __restrict__ x, unsigned short* __restrict__ xb) {
  const int z = blockIdx.z;
  const int tx = threadIdx.x, ty = threadIdx.y;   // (32, 8)
  if (z >= 4) {
    int chunk = (z - 4) * 1024 + blockIdx.y * 32 + blockIdx.x;
    size_t i = ((size_t)chunk * 256 + ty * 32 + tx) * 4;
    float4 v = *(const float4*)(x + i);
    u16x4 o;
    o[0] = f2bf(v.x); o[1] = f2bf(v.y); o[2] = f2bf(v.z); o[3] = f2bf(v.w);
    *(u16x4*)(xb + i) = o;
    return;
  }
  const float* W = (z == 0) ? W0 : (z == 1) ? W1 : (z == 2) ? W2 : W3;
  unsigned short* T = (z == 0) ? T0 : (z == 1) ? T1 : (z == 2) ? T2 : T3;
  __shared__ unsigned short buf[32][33];
  const int k0 = blockIdx.x * 32, n0 = blockIdx.y * 32;
#pragma unroll
  for (int j = 0; j < 4; ++j) {
    int r = ty + j * 8;
    buf[r][tx] = f2bf(W[(size_t)(k0 + r) * 1024 + n0 + tx]);
  }
  __syncthreads();
#pragma unroll
  for (int j = 0; j < 4; ++j) {
    int c = ty + j * 8;
    T[(size_t)(n0 + c) * 1024 + k0 + tx] = buf[tx][c];
  }
}

// ---------------- shared GEMM main loop (BK=32, gload_lds + dbuf) ------------
DI void stage_gemm(const unsigned short* __restrict__ src, unsigned short* dst,
                   int row0, int k0, int tid, int wid) {
#pragma unroll
  for (int i = 0; i < 2; ++i) {
    int T = i * 256 + tid;
    int row = T >> 2, ch = T & 3;
    int sch = ch ^ (row & 3);
    gload16(&src[(size_t)(row0 + row) * 1024 + k0 + sch * 8],
            &dst[(i * 256 + wid * 64) * 8]);
  }
}

DI void gemm_main(const unsigned short* __restrict__ A,
                  const unsigned short* __restrict__ Bm,
                  unsigned short* As, unsigned short* Bs,
                  int m0, int n0, f32x4 acc[4][4]) {
  const int tid = threadIdx.x;
  const int lane = tid & 63, wid = tid >> 6;
  const int wr = wid >> 1, wc = wid & 1;
  const int g = lane >> 4, lq = lane & 15;

  stage_gemm(A, As, m0, 0, tid, wid);
  stage_gemm(Bm, Bs, n0, 0, tid, wid);
  __syncthreads();
  int buf = 0;
  for (int k0 = 0; k0 < 1024; k0 += 32) {
    if (k0 + 32 < 1024) {
      stage_gemm(A, As + (buf ^ 1) * 4096, m0, k0 + 32, tid, wid);
      stage_gemm(Bm, Bs + (buf ^ 1) * 4096, n0, k0 + 32, tid, wid);
    }
    const unsigned short* Ab = As + buf * 4096;
    const unsigned short* Bb = Bs + buf * 4096;
    U8 af[4], bfr[4];
#pragma unroll
    for (int f = 0; f < 4; ++f) {
      af[f].u  = *(const u16x8*)&Ab[(wr * 64 + f * 16 + lq) * 32 + ((g ^ (lq & 3)) * 8)];
      bfr[f].u = *(const u16x8*)&Bb[(wc * 64 + f * 16 + lq) * 32 + ((g ^ (lq & 3)) * 8)];
    }
#pragma unroll
    for (int i = 0; i < 4; ++i)
#pragma unroll
      for (int j = 0; j < 4; ++j)
        acc[i][j] = __builtin_amdgcn_mfma_f32_16x16x32_bf16(af[i].b, bfr[j].b,
                                                            acc[i][j], 0, 0, 0);
    __syncthreads();
    buf ^= 1;
  }
}

// ---------------- kernel 1: QKV projection (LDS-restaged epilogue) ----------
__global__ __launch_bounds__(256) void k_gemm_qkv(
    const unsigned short* __restrict__ xb,
    const unsigned short* __restrict__ Wqt, const unsigned short* __restrict__ Wkt,
    const unsigned short* __restrict__ Wvt,
    const float* __restrict__ bq, const float* __restrict__ bk,
    const float* __restrict__ bv,
    unsigned short* __restrict__ Qo, unsigned short* __restrict__ Ko,
    unsigned short* __restrict__ Vto) {
  __shared__ unsigned short Sh[128 * 136];   // dbuf (16384) + epilogue tile
  unsigned short* As = Sh;
  unsigned short* Bs = Sh + 8192;
  const int z = blockIdx.z;
  const unsigned short* Bm = (z == 0) ? Wqt : (z == 1) ? Wkt : Wvt;
  const float* bias = (z == 0) ? bq : (z == 1) ? bk : bv;

  f32x4 acc[4][4];
#pragma unroll
  for (int i = 0; i < 4; ++i)
#pragma unroll
    for (int j = 0; j < 4; ++j) acc[i][j] = f32x4{0.f, 0.f, 0.f, 0.f};

  const int m0 = blockIdx.x * 128, n0 = blockIdx.y * 128;
  gemm_main(xb, Bm, As, Bs, m0, n0, acc);

  const int tid = threadIdx.x;
  const int lane = tid & 63, wid = tid >> 6;
  const int wr = wid >> 1, wc = wid & 1;
  const int g = lane >> 4, lq = lane & 15;
  const int bb = m0 >> 11;   // batch (128-row tile within one batch)

#pragma unroll
  for (int j = 0; j < 4; ++j) {
    int col = wc * 64 + j * 16 + lq;
    float bv_ = bias[n0 + col];
#pragma unroll
    for (int i = 0; i < 4; ++i)
#pragma unroll
      for (int r = 0; r < 4; ++r) {
        int row = wr * 64 + i * 16 + g * 4 + r;
        Sh[row * 136 + col] = f2bf(acc[i][j][r] + bv_);
      }
  }
  __syncthreads();

  if (z < 2) {
    unsigned short* dstQK = (z == 0) ? Qo : Ko;
    const int ch = tid & 15, sb = tid >> 4;
#pragma unroll
    for (int it = 0; it < 8; ++it) {
      int s = sb + it * 16;
      u16x8 v = *(const u16x8*)&Sh[s * 136 + ch * 8];
      int gcol = n0 + ch * 8;
      int hh = gcol >> 6, dd = gcol & 63;
      int sr = (m0 + s) & 2047;
      *(u16x8*)&dstQK[(((size_t)(bb * 16 + hh)) * 2048 + sr) * 64 + dd] = v;
    }
  } else {
    const int d = tid & 127, hf = tid >> 7;
    int gcol = n0 + d;
    int hh = gcol >> 6, dd = gcol & 63;
    size_t vrow = ((size_t)(bb * 16 + hh)) * 64 + dd;
#pragma unroll
    for (int it = 0; it < 8; ++it) {
      int s0 = (hf + it * 2) * 8;
      u16x8 vv;
#pragma unroll
      for (int e = 0; e < 8; ++e) vv[e] = Sh[(s0 + e) * 136 + d];
      *(u16x8*)&Vto[vrow * 2048 + (m0 & 2047) + s0] = vv;
    }
  }
}

// ---------------- kernel 3: output projection (fp32 out + bias) ----------------
__global__ __launch_bounds__(256) void k_gemm_out(
    const unsigned short* __restrict__ Ob, const unsigned short* __restrict__ Wot,
    const float* __restrict__ bo, float* __restrict__ out) {
  __shared__ unsigned short As[2 * 4096];
  __shared__ unsigned short Bs[2 * 4096];
  f32x4 acc[4][4];
#pragma unroll
  for (int i = 0; i < 4; ++i)
#pragma unroll
    for (int j = 0; j < 4; ++j) acc[i][j] = f32x4{0.f, 0.f, 0.f, 0.f};

  const int m0 = blockIdx.x * 128, n0 = blockIdx.y * 128;
  gemm_main(Ob, Wot, As, Bs, m0, n0, acc);

  const int lane = threadIdx.x & 63, wid = threadIdx.x >> 6;
  const int wr = wid >> 1, wc = wid & 1;
  const int g = lane >> 4, lq = lane & 15;
#pragma unroll
  for (int j = 0; j < 4; ++j) {
    int col = n0 + wc * 64 + j * 16 + lq;
    float bv_ = bo[col];
#pragma unroll
    for (int i = 0; i < 4; ++i)
#pragma unroll
      for (int r = 0; r < 4; ++r) {
        int row = m0 + wr * 64 + i * 16 + g * 4 + r;
        out[(size_t)row * 1024 + col] = acc[i][j][r] + bv_;
      }
  }
}

// ---------------- kernel 2: flash attention v15 (r17 form) --------------------
template<bool MASKED>
DI void ptile(f32x4 sacc[4], f32x4& lacc, unsigned int pk[4][2],
              int qrow, int kk0, int g) {
  const float SC = 0.18033688011112042f;   // 0.125 * log2(e)
#pragma unroll
  for (int c = 0; c < 4; ++c) {
#pragma unroll
    for (int r = 0; r < 4; ++r) {
      float sv = fabsf(sacc[c][r]) * SC;
      if (MASKED) {
        int k = kk0 + g * 8 + r + 4 * (c & 1) + 32 * (c >> 1);
        sv = (k <= qrow) ? sv : -1e30f;
      }
      float p = exp2f(sv);
      sacc[c][r] = p;
      lacc[r] += p;
    }
    asm("v_cvt_pk_bf16_f32 %0, %1, %2"
        : "=v"(pk[c][0]) : "v"(sacc[c][0]), "v"(sacc[c][1]));
    asm("v_cvt_pk_bf16_f32 %0, %1, %2"
        : "=v"(pk[c][1]) : "v"(sacc[c][2]), "v"(sacc[c][3]));
  }
}

DI void flash_dual(bool complete, int qblk, int t0, int t1, int slot,
                   const unsigned short* __restrict__ Q,
                   const unsigned short* __restrict__ Km,
                   const unsigned short* __restrict__ Vt,
                   unsigned short* __restrict__ O,
                   unsigned short* __restrict__ Pp, float* __restrict__ Lp,
                   unsigned short* Ks0, unsigned short* Vs0,
                   size_t qkbase, size_t vbase, int b, int h,
                   int tid, int wid, int g, int lq) {
  const int lrowA = wid * 32 + lq, lrowB = lrowA + 16;
  const int qrowA = qblk * 128 + lrowA, qrowB = qblk * 128 + lrowB;
  const int diag0 = 2 * qblk;

  auto stage = [&](int bf, int t) {           // 4 gload16/thread
    const int kk0 = t * 64;
#pragma unroll
    for (int i = 0; i < 2; ++i) {
      int T = i * 256 + tid;
      int row = T >> 3, ch = T & 7;
      int sch = ch ^ (row & 7);
      gload16(&Km[qkbase + (size_t)(kk0 + row) * 64 + sch * 8],
              Ks0 + bf * 4096 + (i * 2048 + wid * 512));
      gload16(&Vt[vbase + (size_t)row * 2048 + kk0 + sch * 8],
              Vs0 + bf * 4096 + (i * 2048 + wid * 512));
    }
  };

  U8 aqA0, aqA1, aqB0, aqB1;
  {
    const unsigned short* qp = &Q[qkbase + (size_t)qrowA * 64 + g * 8];
    aqA0.u = *(const u16x8*)qp;
    aqA1.u = *(const u16x8*)(qp + 32);
    const unsigned short* qp2 = &Q[qkbase + (size_t)qrowB * 64 + g * 8];
    aqB0.u = *(const u16x8*)qp2;
    aqB1.u = *(const u16x8*)(qp2 + 32);
  }
  f32x4 laccA = f32x4{0.f, 0.f, 0.f, 0.f}, laccB = f32x4{0.f, 0.f, 0.f, 0.f};
  f32x4 oaccA[4], oaccB[4];
#pragma unroll
  for (int c = 0; c < 4; ++c) {
    oaccA[c] = f32x4{0.f, 0.f, 0.f, 0.f};
    oaccB[c] = f32x4{0.f, 0.f, 0.f, 0.f};
  }

  const int rbase = (lq >> 2) * 8 + (lq & 3);

  stage(0, t0);
  if (t0 + 1 < t1) stage(1, t0 + 1);
  int bi = 0;
  for (int t = t0; t < t1; ++t) {
    if (t + 1 < t1) WAIT_VM4; else WAIT_VM0;
    BARRIER;
    if (t + 2 < t1) {
      int nb = bi + 2; if (nb >= 3) nb -= 3;
      stage(nb, t + 2);
    }
    const unsigned short* Kb = Ks0 + bi * 4096;
    const unsigned short* Vb = Vs0 + bi * 4096;
    const int kk0 = t * 64;
    f32x4 saccA[4], saccB[4];
    __builtin_amdgcn_s_setprio(1);
#pragma unroll
    for (int c = 0; c < 4; ++c) {
      int row = rbase + 4 * (c & 1) + 32 * (c >> 1);
      int r7 = row & 7;
      U8 kf0, kf1;
      kf0.u = *(const u16x8*)&Kb[row * 64 + ((g ^ r7) * 8)];
      kf1.u = *(const u16x8*)&Kb[row * 64 + (((4 + g) ^ r7) * 8)];
      saccA[c] = __builtin_amdgcn_mfma_f32_16x16x32_bf16(kf0.b, aqA0.b,
                                                         f32x4{0.f, 0.f, 0.f, 0.f}, 0, 0, 0);
      saccA[c] = __builtin_amdgcn_mfma_f32_16x16x32_bf16(kf1.b, aqA1.b, saccA[c], 0, 0, 0);
      saccB[c] = __builtin_amdgcn_mfma_f32_16x16x32_bf16(kf0.b, aqB0.b,
                                                         f32x4{0.f, 0.f, 0.f, 0.f}, 0, 0, 0);
      saccB[c] = __builtin_amdgcn_mfma_f32_16x16x32_bf16(kf1.b, aqB1.b, saccB[c], 0, 0, 0);
    }
    __builtin_amdgcn_s_setprio(0);
    unsigned int pkA[4][2], pkB[4][2];
    if (t >= diag0) {
      ptile<true>(saccA, laccA, pkA, qrowA, kk0, g);
      ptile<true>(saccB, laccB, pkB, qrowB, kk0, g);
    } else {
      ptile<false>(saccA, laccA, pkA, qrowA, kk0, g);
      ptile<false>(saccB, laccB, pkB, qrowB, kk0, g);
    }
    __builtin_amdgcn_s_setprio(1);
#pragma unroll
    for (int hh = 0; hh < 2; ++hh) {
      PB pbA, pbB;
      pbA.w[0] = pkA[hh * 2 + 0][0]; pbA.w[1] = pkA[hh * 2 + 0][1];
      pbA.w[2] = pkA[hh * 2 + 1][0]; pbA.w[3] = pkA[hh * 2 + 1][1];
      pbB.w[0] = pkB[hh * 2 + 0][0]; pbB.w[1] = pkB[hh * 2 + 0][1];
      pbB.w[2] = pkB[hh * 2 + 1][0]; pbB.w[3] = pkB[hh * 2 + 1][1];
#pragma unroll
      for (int c = 0; c < 4; ++c) {
        U8 vf;
        vf.u = *(const u16x8*)&Vb[(c * 16 + lq) * 64 + (((hh * 4 + g) ^ (lq & 7)) * 8)];
        oaccA[c] = __builtin_amdgcn_mfma_f32_16x16x32_bf16(vf.b, pbA.b, oaccA[c], 0, 0, 0);
        oaccB[c] = __builtin_amdgcn_mfma_f32_16x16x32_bf16(vf.b, pbB.b, oaccB[c], 0, 0, 0);
      }
    }
    __builtin_amdgcn_s_setprio(0);
    ++bi; if (bi >= 3) bi = 0;
  }

  float lsA = (laccA[0] + laccA[1]) + (laccA[2] + laccA[3]);
  lsA += __shfl_xor(lsA, 16, 64);
  lsA += __shfl_xor(lsA, 32, 64);
  float lsB = (laccB[0] + laccB[1]) + (laccB[2] + laccB[3]);
  lsB += __shfl_xor(lsB, 16, 64);
  lsB += __shfl_xor(lsB, 32, 64);
  if (complete) {
    float invA = 1.0f / lsA, invB = 1.0f / lsB;
#pragma unroll
    for (int c = 0; c < 4; ++c) {
      u16x4 ovA, ovB;
#pragma unroll
      for (int r2 = 0; r2 < 4; ++r2) {
        ovA[r2] = f2bf(oaccA[c][r2] * invA);
        ovB[r2] = f2bf(oaccB[c][r2] * invB);
      }
      *(u16x4*)&O[((size_t)(b * 2048 + qrowA)) * 1024 + h * 64 + c * 16 + g * 4] = ovA;
      *(u16x4*)&O[((size_t)(b * 2048 + qrowB)) * 1024 + h * 64 + c * 16 + g * 4] = ovB;
    }
  } else {
    if (g == 0) {
      Lp[slot * 128 + lrowA] = lsA;
      Lp[slot * 128 + lrowB] = lsB;
    }
    size_t pbase = (size_t)slot * 8192;
#pragma unroll
    for (int c = 0; c < 4; ++c) {
      u16x4 ovA, ovB;
#pragma unroll
      for (int r2 = 0; r2 < 4; ++r2) {
        ovA[r2] = f2bf(oaccA[c][r2]);
        ovB[r2] = f2bf(oaccB[c][r2]);
      }
      *(u16x4*)&Pp[pbase + lrowA * 64 + c * 16 + g * 4] = ovA;
      *(u16x4*)&Pp[pbase + lrowB * 64 + c * 16 + g * 4] = ovB;
    }
  }
  WAIT_VM0;
  BARRIER;
}

__global__ __launch_bounds__(256) void k_flash(
    const unsigned short* __restrict__ Q, const unsigned short* __restrict__ Km,
    const unsigned short* __restrict__ Vt, unsigned short* __restrict__ O,
    unsigned short* __restrict__ Pp, float* __restrict__ Lp) {
  __shared__ unsigned short Ks[3 * 4096];
  __shared__ unsigned short Vs[3 * 4096];
  const int tid = threadIdx.x;
  const int lane = tid & 63, wid = tid >> 6;
  const int g = lane >> 4, lq = lane & 15;
  const int bid = blockIdx.x;               // 512 blocks
  const int xcd = bid & 7, idx = bid >> 3;  // 64 per XCD
  const int bh = xcd * 4 + (idx >> 4);      // 4 bh per XCD
  const int rr = idx & 15;
  const int p = rr >> 1, sp = rr & 1;
  const int mp = 15 - p;
  const int b = bh >> 4, h = bh & 15;
  const size_t qkbase = (size_t)bh * 2048 * 64;
  const size_t vbase = (size_t)bh * 64 * 2048;

  if (sp == 0) {
    flash_dual(true, p, 0, 2 * p + 2, 0, Q, Km, Vt, O, Pp, Lp,
               Ks, Vs, qkbase, vbase, b, h, tid, wid, g, lq);
    flash_dual(false, mp, 0, 15 - 2 * p, (bh * 8 + p) * 2 + 0, Q, Km, Vt, O, Pp, Lp,
               Ks, Vs, qkbase, vbase, b, h, tid, wid, g, lq);
  } else {
    flash_dual(false, mp, 15 - 2 * p, 32 - 2 * p, (bh * 8 + p) * 2 + 1, Q, Km, Vt, O, Pp, Lp,
               Ks, Vs, qkbase, vbase, b, h, tid, wid, g, lq);
  }
}

// ---------------- kernel 2b: combine mirror partials (128-row slots) ---------
__global__ __launch_bounds__(256) void k_combine(
    const unsigned short* __restrict__ Pp, const float* __restrict__ Lp,
    unsigned short* __restrict__ O) {
  int gid = blockIdx.x * 256 + threadIdx.x;   // 524288 threads
  int dv4 = gid & 15;
  int q   = (gid >> 4) & 127;
  int pi  = (gid >> 11) & 7;
  int bh  = gid >> 14;
  int slot0 = (bh * 8 + pi) * 2;
  size_t base = (size_t)slot0 * 8192 + q * 64 + dv4 * 4;
  u16x4 a = *(const u16x4*)&Pp[base];
  u16x4 c = *(const u16x4*)&Pp[base + 8192];
  float l = Lp[slot0 * 128 + q] + Lp[(slot0 + 1) * 128 + q];
  float inv = 1.0f / l;
  u16x4 o;
#pragma unroll
  for (int r = 0; r < 4; ++r) o[r] = f2bf((bf2f(a[r]) + bf2f(c[r])) * inv);
  int b = bh >> 4, h = bh & 15;
  int srow = (15 - pi) * 128 + q;
  *(u16x4*)&O[((size_t)(b * 2048 + srow)) * 1024 + h * 64 + dv4 * 4] = o;
}

// ---------------- launch ----------------
extern "C" void kernel_launch(void* const* d_in, const int* in_sizes, int n_in,
                              void* d_out, int out_size, void* d_ws, size_t ws_size,
                              hipStream_t stream) {
  const float* x  = (const float*)d_in[0];
  const float* Wq = (const float*)d_in[1];
  const float* bq = (const float*)d_in[2];
  const float* Wk = (const float*)d_in[3];
  const float* bk = (const float*)d_in[4];
  const float* Wv = (const float*)d_in[5];
  const float* bv = (const float*)d_in[6];
  const float* Wo = (const float*)d_in[7];
  const float* bo = (const float*)d_in[8];
  float* out = (float*)d_out;

  char* ws = (char*)d_ws;
  const size_t MB = 1024 * 1024;
  unsigned short* xb   = (unsigned short*)(ws + 0 * MB);   // 8 MB (dead after qkv)
  unsigned short* Wqt  = (unsigned short*)(ws + 8 * MB);   // 2 MB (dead after qkv)
  unsigned short* Wkt  = (unsigned short*)(ws + 10 * MB);  // 2 MB
  unsigned short* Wvt  = (unsigned short*)(ws + 12 * MB);  // 2 MB
  unsigned short* Wot  = (unsigned short*)(ws + 14 * MB);  // 2 MB (used by out-proj)
  unsigned short* Qws  = (unsigned short*)(ws + 16 * MB);  // 8 MB
  unsigned short* Kws  = (unsigned short*)(ws + 24 * MB);  // 8 MB
  unsigned short* Vtws = (unsigned short*)(ws + 32 * MB);  // 8 MB
  unsigned short* Ows  = (unsigned short*)(ws + 40 * MB);  // 8 MB
  unsigned short* Pp   = (unsigned short*)(ws + 0 * MB);   // 8 MB, overlays xb
  float*          Lp   = (float*)(ws + 8 * MB);            // 256 KB, overlays Wqt

  k_prep<<<dim3(32, 32, 8), dim3(32, 8), 0, stream>>>(Wq, Wk, Wv, Wo,
                                                      Wqt, Wkt, Wvt, Wot, x, xb);
  k_gemm_qkv<<<dim3(32, 8, 3), 256, 0, stream>>>(xb, Wqt, Wkt, Wvt, bq, bk, bv,
                                                 Qws, Kws, Vtws);
  k_flash<<<512, 256, 0, stream>>>(Qws, Kws, Vtws, Ows, Pp, Lp);
  k_combine<<<2048, 256, 0, stream>>>(Pp, Lp, Ows);
  k_gemm_out<<<dim3(32, 8), 256, 0, stream>>>(Ows, Wot, bo, out);
}